// Round 1
// baseline (1351.345 us; speedup 1.0000x reference)
//
#include <hip/hip_runtime.h>

#define S_LEN  1024
#define D_KK   64
#define N_HEAD 96   // B*H = 8*12
#define BQ     16   // q-rows per block
#define TK     128  // K rows staged per QK tile  -> kt = 64x129 floats = 33.0 KB
#define NT_QK  (S_LEN / TK)   // 8 QK tiles
#define NCHUNK (S_LEN / 64)   // 16 PV chunks (one chunk == one j-slot of s[])

// Fused: scores + mask + softmax + attn-write + context, one kernel.
// block = 256 threads (4 waves); 16 q-rows/block, 4 rows/wave.
// Lane l holds probabilities for k = l + 64*j, j = 0..15 (full row in regs).
//
// LDS (36.5 KB -> 4 blocks/CU, 16 waves/CU):
//   smA: phase1 K^T tile [d][k] stride 129  |  phase2 V tile [k][d] stride 68
//   smB: phase1 Q tile   [r][d] stride 68   |  phase2 P tile [16 rows][k] stride 68
__global__ __launch_bounds__(256, 4) void attn_fused_kernel(
    const float* __restrict__ Qg, const float* __restrict__ Kg,
    const float* __restrict__ Vg, const int* __restrict__ maskg,
    float* __restrict__ attng, float* __restrict__ ctxg)
{
    __shared__ float smA[64 * 129];   // 33024 B (>= 64*68 = 17408 B for V tile)
    __shared__ float smB[16 * 68];    //  4352 B (== 16*68 for P tile)

    const int t     = threadIdx.x;
    const int lane  = t & 63;
    const int wave  = t >> 6;
    const int head  = blockIdx.y;
    const int q0    = blockIdx.x * BQ;
    const int rbase = wave << 2;

    // ---- stage Q tile (16 x 64), coalesced float4 ----
    {
        const int r  = t >> 4;
        const int d0 = (t & 15) << 2;
        const float4 qv = *(const float4*)(Qg + ((size_t)head * S_LEN + q0 + r) * D_KK + d0);
        smB[r * 68 + d0 + 0] = qv.x;
        smB[r * 68 + d0 + 1] = qv.y;
        smB[r * 68 + d0 + 2] = qv.z;
        smB[r * 68 + d0 + 3] = qv.w;
    }

    float s[4][16];
    #pragma unroll
    for (int r = 0; r < 4; ++r)
        #pragma unroll
        for (int j = 0; j < 16; ++j) s[r][j] = 0.f;

    // ---- Phase 1: scores = Q K^T (accumulate straight into s[][]) ----
    #pragma unroll
    for (int kt_i = 0; kt_i < NT_QK; ++kt_i) {
        __syncthreads();
        // stage K^T tile: global coalesced float4; LDS writes 2-way (free, pad 129)
        {
            const int d0 = (t & 15) << 2;
            const int kb = t >> 4;
            #pragma unroll
            for (int c = 0; c < TK / 16; ++c) {
                const int kl = c * 16 + kb;
                const float4 kv = *(const float4*)(Kg + ((size_t)head * S_LEN + kt_i * TK + kl) * D_KK + d0);
                smA[(d0 + 0) * 129 + kl] = kv.x;
                smA[(d0 + 1) * 129 + kl] = kv.y;
                smA[(d0 + 2) * 129 + kl] = kv.z;
                smA[(d0 + 3) * 129 + kl] = kv.w;
            }
        }
        __syncthreads();

        #pragma unroll
        for (int d0 = 0; d0 < D_KK; d0 += 4) {
            float4 qv[4];
            #pragma unroll
            for (int r = 0; r < 4; ++r)
                qv[r] = *(const float4*)(&smB[(rbase + r) * 68 + d0]);   // broadcast
            #pragma unroll
            for (int dd = 0; dd < 4; ++dd) {
                const float k0v = smA[(d0 + dd) * 129 + lane];           // 2-way (free)
                const float k1v = smA[(d0 + dd) * 129 + lane + 64];
                #pragma unroll
                for (int r = 0; r < 4; ++r) {
                    const float qd = (&qv[r].x)[dd];
                    s[r][2 * kt_i + 0] = fmaf(qd, k0v, s[r][2 * kt_i + 0]);
                    s[r][2 * kt_i + 1] = fmaf(qd, k1v, s[r][2 * kt_i + 1]);
                }
            }
        }
    }

    // ---- mask + softmax + attn write (streamed once -> nontemporal) ----
    #pragma unroll
    for (int r = 0; r < 4; ++r) {
        const int q = q0 + rbase + r;
        const int*  mrow = maskg + ((size_t)head * S_LEN + q) * S_LEN;
        float*      arow = attng + ((size_t)head * S_LEN + q) * S_LEN;
        float m = -3.0e38f;
        #pragma unroll
        for (int j = 0; j < 16; ++j) {
            const int mk = __builtin_nontemporal_load(&mrow[lane + 64 * j]);
            float v = s[r][j] * 0.125f;                   // * 1/sqrt(64)
            if (mk) v = -1.0e9f;
            s[r][j] = v;
            m = fmaxf(m, v);
        }
        #pragma unroll
        for (int off = 32; off >= 1; off >>= 1)
            m = fmaxf(m, __shfl_xor(m, off, 64));
        float l = 0.0f;
        #pragma unroll
        for (int j = 0; j < 16; ++j) {
            s[r][j] = __expf(s[r][j] - m);
            l += s[r][j];
        }
        #pragma unroll
        for (int off = 32; off >= 1; off >>= 1)
            l += __shfl_xor(l, off, 64);
        const float inv = 1.0f / l;
        #pragma unroll
        for (int j = 0; j < 16; ++j) {
            s[r][j] *= inv;                                // s[] now = attn probs
            __builtin_nontemporal_store(s[r][j], &arow[lane + 64 * j]);
        }
    }

    // ---- Phase 2: context = P @ V, chunked over k (chunk c == j-slot c) ----
    float acc0 = 0.f, acc1 = 0.f, acc2 = 0.f, acc3 = 0.f;
    const int qr = lane >> 4;        // q-row within wave (0..3)
    const int tx = lane & 15;        // d-group (4 floats)

    #pragma unroll                   // MUST unroll: s[r][c2] needs static index
    for (int c2 = 0; c2 < NCHUNK; ++c2) {
        __syncthreads();             // prev chunk's (or kt/qs) readers done
        // stage V chunk 64 x 64 (coalesced float4)
        #pragma unroll
        for (int p_ = 0; p_ < 4; ++p_) {
            const int i  = t + 256 * p_;
            const int k  = i >> 4;
            const int d0 = (i & 15) << 2;
            const float4 v = *(const float4*)(Vg + ((size_t)head * S_LEN + c2 * 64 + k) * D_KK + d0);
            *(float4*)(&smA[k * 68 + d0]) = v;
        }
        // dump this wave's P slice: row (rbase+r), k = lane  (banks l%32, free)
        #pragma unroll
        for (int r = 0; r < 4; ++r)
            smB[(rbase + r) * 68 + lane] = s[r][c2];
        __syncthreads();

        #pragma unroll
        for (int kk = 0; kk < 16; ++kk) {
            const float4 a4 = *(const float4*)(&smB[(rbase + qr) * 68 + 4 * kk]); // 4-addr, conflict-free
            #pragma unroll
            for (int e = 0; e < 4; ++e) {
                const float  a = (&a4.x)[e];
                const float4 v = *(const float4*)(&smA[(4 * kk + e) * 68 + (tx << 2)]); // 256B contig, bcast
                acc0 = fmaf(a, v.x, acc0);
                acc1 = fmaf(a, v.y, acc1);
                acc2 = fmaf(a, v.z, acc2);
                acc3 = fmaf(a, v.w, acc3);
            }
        }
    }

    float4 o; o.x = acc0; o.y = acc1; o.z = acc2; o.w = acc3;
    *(float4*)(ctxg + ((size_t)head * S_LEN + q0 + rbase + qr) * D_KK + (tx << 2)) = o;
}

extern "C" void kernel_launch(void* const* d_in, const int* in_sizes, int n_in,
                              void* d_out, int out_size, void* d_ws, size_t ws_size,
                              hipStream_t stream) {
    const float* Q    = (const float*)d_in[0];
    const float* K    = (const float*)d_in[1];
    const float* V    = (const float*)d_in[2];
    const int*   mask = (const int*)d_in[3];

    float* ctx  = (float*)d_out;                                // [B,H,S,D] first
    float* attn = ctx + (size_t)N_HEAD * S_LEN * D_KK;          // then [B,H,S,S]

    dim3 grid(S_LEN / BQ, N_HEAD);
    attn_fused_kernel<<<grid, 256, 0, stream>>>(Q, K, V, mask, attn, ctx);
}

// Round 2
// 1185.543 us; speedup vs baseline: 1.1399x; 1.1399x over previous
//
#include <hip/hip_runtime.h>

#define S_LEN  1024
#define D_KK   64
#define N_HEAD 96   // B*H = 8*12
#define BQ     16   // q-rows per block
#define TK     128  // K rows per QK tile
#define NT_QK  (S_LEN / TK)   // 8 QK tiles
#define CHK    128            // PV k-chunk
#define NCH    (S_LEN / CHK)  // 8 PV chunks
#define KSTR   129            // K^T LDS stride (floats)
#define QSTR   132            // Q / P LDS stride (floats; >=128, pad 4)
#define VSTR   68             // V LDS stride (floats)

// Fused: scores + mask + softmax + attn-write + context, one kernel.
// block = 256 threads (4 waves); 16 q-rows/block, 4 rows/wave.
// Lane l holds probabilities for k = l + 64*j, j = 0..15 (full row in 64 VGPRs).
//
// LDS (43,264 B -> 2 blocks/CU at launch_bounds(256,2); no spill, 256-VGPR cap):
//   smA: phase1 K^T tile [64][129] | phase2 V chunk [128][68]  (34,816 B)
//   smB: phase1 Q tile  [16][132]  | phase2 P chunk [16][132]  ( 8,448 B)
//        (each wave dumps/reads only its OWN 4 P-rows -> no cross-wave hazard)
__global__ __launch_bounds__(256, 2) void attn_fused_kernel(
    const float* __restrict__ Qg, const float* __restrict__ Kg,
    const float* __restrict__ Vg, const int* __restrict__ maskg,
    float* __restrict__ attng, float* __restrict__ ctxg)
{
    __shared__ float smA[CHK * VSTR];   // 8704 floats = 34,816 B (>= 64*129)
    __shared__ float smB[BQ * QSTR];    // 2112 floats =  8,448 B

    const int t     = threadIdx.x;
    const int lane  = t & 63;
    const int wave  = t >> 6;
    const int head  = blockIdx.y;
    const int q0    = blockIdx.x * BQ;
    const int rbase = wave << 2;

    // ---- stage Q tile (16 x 64), coalesced float4 ----
    {
        const int r  = t >> 4;
        const int d0 = (t & 15) << 2;
        const float4 qv = *(const float4*)(Qg + ((size_t)head * S_LEN + q0 + r) * D_KK + d0);
        smB[r * QSTR + d0 + 0] = qv.x;
        smB[r * QSTR + d0 + 1] = qv.y;
        smB[r * QSTR + d0 + 2] = qv.z;
        smB[r * QSTR + d0 + 3] = qv.w;
    }

    float s[4][16];
    #pragma unroll
    for (int r = 0; r < 4; ++r)
        #pragma unroll
        for (int j = 0; j < 16; ++j) s[r][j] = 0.f;

    // ---- Phase 1: scores = Q K^T (accumulate straight into s[][]) ----
    #pragma unroll
    for (int kt_i = 0; kt_i < NT_QK; ++kt_i) {
        __syncthreads();
        // stage K^T tile: global coalesced float4; LDS writes 2-way (free, pad 129)
        {
            const int d0 = (t & 15) << 2;
            const int kb = t >> 4;
            #pragma unroll
            for (int c = 0; c < TK / 16; ++c) {
                const int kl = c * 16 + kb;
                const float4 kv = *(const float4*)(Kg + ((size_t)head * S_LEN + kt_i * TK + kl) * D_KK + d0);
                smA[(d0 + 0) * KSTR + kl] = kv.x;
                smA[(d0 + 1) * KSTR + kl] = kv.y;
                smA[(d0 + 2) * KSTR + kl] = kv.z;
                smA[(d0 + 3) * KSTR + kl] = kv.w;
            }
        }
        __syncthreads();

        #pragma unroll
        for (int d0 = 0; d0 < D_KK; d0 += 4) {
            float4 qv[4];
            #pragma unroll
            for (int r = 0; r < 4; ++r)
                qv[r] = *(const float4*)(&smB[(rbase + r) * QSTR + d0]);  // broadcast
            #pragma unroll
            for (int dd = 0; dd < 4; ++dd) {
                const float k0v = smA[(d0 + dd) * KSTR + lane];           // 2-way (free)
                const float k1v = smA[(d0 + dd) * KSTR + lane + 64];
                #pragma unroll
                for (int r = 0; r < 4; ++r) {
                    const float qd = (&qv[r].x)[dd];
                    s[r][2 * kt_i + 0] = fmaf(qd, k0v, s[r][2 * kt_i + 0]);
                    s[r][2 * kt_i + 1] = fmaf(qd, k1v, s[r][2 * kt_i + 1]);
                }
            }
        }
    }

    // ---- mask + softmax + attn write (streamed once -> nontemporal) ----
    #pragma unroll
    for (int r = 0; r < 4; ++r) {
        const int q = q0 + rbase + r;
        const int*  mrow = maskg + ((size_t)head * S_LEN + q) * S_LEN;
        float*      arow = attng + ((size_t)head * S_LEN + q) * S_LEN;
        float m = -3.0e38f;
        #pragma unroll
        for (int j = 0; j < 16; ++j) {
            const int mk = __builtin_nontemporal_load(&mrow[lane + 64 * j]);
            float v = s[r][j] * 0.125f;                   // * 1/sqrt(64)
            if (mk) v = -1.0e9f;
            s[r][j] = v;
            m = fmaxf(m, v);
        }
        #pragma unroll
        for (int off = 32; off >= 1; off >>= 1)
            m = fmaxf(m, __shfl_xor(m, off, 64));
        float l = 0.0f;
        #pragma unroll
        for (int j = 0; j < 16; ++j) {
            s[r][j] = __expf(s[r][j] - m);
            l += s[r][j];
        }
        #pragma unroll
        for (int off = 32; off >= 1; off >>= 1)
            l += __shfl_xor(l, off, 64);
        const float inv = 1.0f / l;
        #pragma unroll
        for (int j = 0; j < 16; ++j) {
            s[r][j] *= inv;                                // s[] now = attn probs
            __builtin_nontemporal_store(s[r][j], &arow[lane + 64 * j]);
        }
    }

    // ---- Phase 2: context = P @ V, 8 chunks of 128 k ----
    // Lane owns 1 q-row (qr) x 4 d (tx). P read as b128 (4 probs / LDS instr).
    float acc0 = 0.f, acc1 = 0.f, acc2 = 0.f, acc3 = 0.f;
    const int qr = lane >> 4;        // q-row within wave (0..3)
    const int tx = lane & 15;        // d-group (4 floats)

    #pragma unroll                   // MUST unroll: s[r][2c] needs static index
    for (int c = 0; c < NCH; ++c) {
        __syncthreads();             // prev chunk's (or phase-1) smA readers done
        // stage V chunk 128 x 64 (coalesced float4)
        #pragma unroll
        for (int p_ = 0; p_ < 8; ++p_) {
            const int i  = t + 256 * p_;
            const int k  = i >> 4;
            const int d0 = (i & 15) << 2;
            const float4 v = *(const float4*)(Vg + ((size_t)head * S_LEN + c * CHK + k) * D_KK + d0);
            *(float4*)(&smA[k * VSTR + d0]) = v;
        }
        // dump this wave's P slice (own rows only): k-local = lane, 64+lane
        #pragma unroll
        for (int r = 0; r < 4; ++r) {
            smB[(rbase + r) * QSTR + lane]      = s[r][2 * c + 0];
            smB[(rbase + r) * QSTR + 64 + lane] = s[r][2 * c + 1];
        }
        __syncthreads();             // V chunk visible

        const float* prow = &smB[(rbase + qr) * QSTR];
        #pragma unroll 4
        for (int k4 = 0; k4 < CHK / 4; ++k4) {
            const float4 a4 = *(const float4*)(prow + 4 * k4);          // 4-addr, bcast-16
            #pragma unroll
            for (int e = 0; e < 4; ++e) {
                const float  a = (&a4.x)[e];
                const float4 v = *(const float4*)(&smA[(4 * k4 + e) * VSTR + (tx << 2)]); // 256B contig
                acc0 = fmaf(a, v.x, acc0);
                acc1 = fmaf(a, v.y, acc1);
                acc2 = fmaf(a, v.z, acc2);
                acc3 = fmaf(a, v.w, acc3);
            }
        }
    }

    float4 o; o.x = acc0; o.y = acc1; o.z = acc2; o.w = acc3;
    *(float4*)(ctxg + ((size_t)head * S_LEN + q0 + rbase + qr) * D_KK + (tx << 2)) = o;
}

extern "C" void kernel_launch(void* const* d_in, const int* in_sizes, int n_in,
                              void* d_out, int out_size, void* d_ws, size_t ws_size,
                              hipStream_t stream) {
    const float* Q    = (const float*)d_in[0];
    const float* K    = (const float*)d_in[1];
    const float* V    = (const float*)d_in[2];
    const int*   mask = (const int*)d_in[3];

    float* ctx  = (float*)d_out;                                // [B,H,S,D] first
    float* attn = ctx + (size_t)N_HEAD * S_LEN * D_KK;          // then [B,H,S,S]

    dim3 grid(S_LEN / BQ, N_HEAD);
    attn_fused_kernel<<<grid, 256, 0, stream>>>(Q, K, V, mask, attn, ctx);
}